// Round 20
// baseline (117.564 us; speedup 1.0000x reference)
//
#include <hip/hip_runtime.h>
#include <hip/hip_bf16.h>
#include <math.h>

// Problem constants
#define B_SZ   2
#define SEQ    2048
#define DM     1024
#define NH     16
#define DH     64
#define MROWS  (B_SZ * SEQ)      // 4096
#define DQKV   (3 * DM)          // 3072, interleaved qkv row stride

typedef __attribute__((ext_vector_type(8))) short short8;
typedef __attribute__((ext_vector_type(4))) float f32x4;
typedef __attribute__((ext_vector_type(16))) float f32x16;
typedef __attribute__((ext_vector_type(4))) unsigned short us4;
typedef __attribute__((ext_vector_type(2))) unsigned int u32x2;

__device__ __forceinline__ float b2f(unsigned short u) {
    union { float f; unsigned int i; } x; x.i = ((unsigned int)u) << 16; return x.f;
}
__device__ __forceinline__ unsigned short f2b(float f) {
    union { float f; unsigned int i; } x; x.f = f;
    return (unsigned short)((x.i + 0x7fffu + ((x.i >> 16) & 1u)) >> 16);
}
__device__ __forceinline__ unsigned int pk2b(float a, float b) {
    float2 f2; f2.x = a; f2.y = b;
    __hip_bfloat162 hb = __float22bfloat162_rn(f2);
    return *reinterpret_cast<unsigned int*>(&hb);
}
__device__ __forceinline__ float fexp2(float x) {
    float r; asm("v_exp_f32 %0, %1" : "=v"(r) : "v"(x)); return r;
}
__device__ __forceinline__ void swap32(unsigned int& a, unsigned int& b) {
    asm("v_permlane32_swap_b32 %0, %1" : "+v"(a), "+v"(b));
}

// async global->LDS, 16B per lane; lds base must be wave-uniform (HW adds lane*16)
__device__ __forceinline__ void gload_lds16(const unsigned short* g, unsigned short* lds_base_uniform) {
    __builtin_amdgcn_global_load_lds(
        (const __attribute__((address_space(1))) unsigned int*)g,
        (__attribute__((address_space(3))) unsigned int*)lds_base_uniform,
        16, 0, 0);
}

// ---------------------------------------------------------------------------
// One-shot prep: conversions + RoPE table.
// ---------------------------------------------------------------------------
#define NX4 (MROWS * DM / 4)     // 2^20 vec4
#define NW4 (DM * DM / 4)        // 2^18 vec4

__global__ __launch_bounds__(256) void cvt_all(const float* __restrict__ x,
                                               const float* __restrict__ wq,
                                               const float* __restrict__ wk,
                                               const float* __restrict__ wv,
                                               const float* __restrict__ wo,
                                               unsigned short* __restrict__ xb,
                                               unsigned short* __restrict__ wqkv,
                                               unsigned short* __restrict__ wob,
                                               float* __restrict__ tab) {
    const int i = blockIdx.x * 256 + threadIdx.x;
    const int ncvt = NX4 + 4 * NW4;
    if (i < ncvt) {
        const float* src; unsigned short* dst; int off;
        if (i < NX4) { src = x; dst = xb; off = i; }
        else {
            int j = i - NX4;
            int w = j >> 18;
            off = j & (NW4 - 1);
            src = (w == 0) ? wq : (w == 1) ? wk : (w == 2) ? wv : wo;
            dst = (w < 3) ? wqkv + (size_t)w * DM * DM : wob;
        }
        float4 v = reinterpret_cast<const float4*>(src)[off];
        us4 o = { f2b(v.x), f2b(v.y), f2b(v.z), f2b(v.w) };
        reinterpret_cast<us4*>(dst)[off] = o;
    } else {
        int t = i - ncvt;               // [0, SEQ*32)
        if (t < SEQ * 32) {
            int s = t >> 5, fi = t & 31;
            float inv = powf(10000.0f, -(float)fi / 32.0f);
            float ang = (float)s * inv;
            tab[2 * t]     = cosf(ang);
            tab[2 * t + 1] = sinf(ang);
        }
    }
}

// ---------------------------------------------------------------------------
// Triple-buffered counted-vmcnt bf16 MFMA GEMMs (unchanged).
// ---------------------------------------------------------------------------
#define BM 128
#define BN 128
#define BK 32

__global__ __launch_bounds__(256, 2) void gemm_out(const unsigned short* __restrict__ A,
                                                   const unsigned short* __restrict__ B,
                                                   float* __restrict__ Cout) {
    __shared__ unsigned short As[3][128 * BK];   // 3 x 8 KB
    __shared__ unsigned short Bs[3][64 * BK];    // 3 x 4 KB
    const int tid  = threadIdx.x;
    const int lane = tid & 63, wid = tid >> 6;
    const int lm = lane & 15, lg = lane >> 4;
    const int brow = blockIdx.y * 128, bcol = blockIdx.x * 64;
    const int K = DM, N = DM;
    const int NT = K / BK;     // 32

    f32x4 acc[2][4] = {};

    const int rA  = tid >> 2;
    const int kc8 = (tid & 3) * 8;
    const unsigned short* gA0 = A + (size_t)(brow + rA) * K + kc8;
    const unsigned short* gA1 = A + (size_t)(brow + 64 + rA) * K + kc8;
    const unsigned short* gB0 = B + (size_t)(bcol + rA) * K + kc8;
    const int la = wid * 512;

#define OSTAGE(t, bi)                                        \
    {                                                        \
        const int _o = (t) * BK;                             \
        gload_lds16(gA0 + _o, &As[bi][la]);                  \
        gload_lds16(gA1 + _o, &As[bi][2048 + la]);           \
        gload_lds16(gB0 + _o, &Bs[bi][la]);                  \
    }

    OSTAGE(0, 0);
    OSTAGE(1, 1);
    asm volatile("s_waitcnt vmcnt(3)" ::: "memory");
    __builtin_amdgcn_s_barrier();
    asm volatile("" ::: "memory");

    int cb = 0, sb = 2;
    for (int k = 0; k < NT; ++k) {
        if (k + 2 < NT) OSTAGE(k + 2, sb);
        short8 a[2], b[4];
#pragma unroll
        for (int m = 0; m < 2; ++m)
            a[m] = *reinterpret_cast<const short8*>(&As[cb][(wid * 32 + m * 16 + lm) * BK + lg * 8]);
#pragma unroll
        for (int n = 0; n < 4; ++n)
            b[n] = *reinterpret_cast<const short8*>(&Bs[cb][(n * 16 + lm) * BK + lg * 8]);
#pragma unroll
        for (int m = 0; m < 2; ++m)
#pragma unroll
            for (int n = 0; n < 4; ++n)
                acc[m][n] = __builtin_amdgcn_mfma_f32_16x16x32_bf16(a[m], b[n], acc[m][n], 0, 0, 0);
        if (k + 1 < NT) {
            if (k + 2 < NT) asm volatile("s_waitcnt vmcnt(3)" ::: "memory");
            else            asm volatile("s_waitcnt vmcnt(0)" ::: "memory");
            __builtin_amdgcn_s_barrier();
            asm volatile("" ::: "memory");
        }
        cb = (cb == 2) ? 0 : cb + 1;
        sb = (sb == 2) ? 0 : sb + 1;
    }
#undef OSTAGE

#pragma unroll
    for (int m = 0; m < 2; ++m) {
#pragma unroll
        for (int r = 0; r < 4; ++r) {
            const size_t base = (size_t)(brow + wid * 32 + m * 16 + lg * 4 + r) * N + bcol + lm;
#pragma unroll
            for (int n = 0; n < 4; ++n)
                Cout[base + n * 16] = acc[m][n][r];
        }
    }
}

__global__ __launch_bounds__(256, 2) void gemm_qkv(const unsigned short* __restrict__ A,
                                                   const unsigned short* __restrict__ B,
                                                   unsigned short* __restrict__ qkv,
                                                   unsigned short* __restrict__ vT,
                                                   const float* __restrict__ tab) {
    __shared__ unsigned short As[3][BM * BK];   // 3 x 8 KB
    __shared__ unsigned short Bs[3][BN * BK];   // 3 x 8 KB
    const int tid  = threadIdx.x;
    const int lane = tid & 63, wid = tid >> 6;
    const int wr = wid >> 1, wc = wid & 1;
    const int lm = lane & 15, lg = lane >> 4;
    const int brow = blockIdx.y * BM, bcol = blockIdx.x * BN;
    const int K = DM;
    const int NT = K / BK;     // 32

    f32x4 acc[4][4] = {};

    const int rA  = tid >> 2;
    const int kc8 = (tid & 3) * 8;
    const unsigned short* gA0 = A + (size_t)(brow + rA) * K + kc8;
    const unsigned short* gA1 = A + (size_t)(brow + 64 + rA) * K + kc8;
    const unsigned short* gB0 = B + (size_t)(bcol + rA) * K + kc8;
    const unsigned short* gB1 = B + (size_t)(bcol + 64 + rA) * K + kc8;
    const int la = wid * 512;

#define QSTAGE(t, bi)                                        \
    {                                                        \
        const int _o = (t) * BK;                             \
        gload_lds16(gA0 + _o, &As[bi][la]);                  \
        gload_lds16(gA1 + _o, &As[bi][2048 + la]);           \
        gload_lds16(gB0 + _o, &Bs[bi][la]);                  \
        gload_lds16(gB1 + _o, &Bs[bi][2048 + la]);           \
    }

    QSTAGE(0, 0);
    QSTAGE(1, 1);
    asm volatile("s_waitcnt vmcnt(4)" ::: "memory");
    __builtin_amdgcn_s_barrier();
    asm volatile("" ::: "memory");

    int cb = 0, sb = 2;
    for (int k = 0; k < NT; ++k) {
        if (k + 2 < NT) QSTAGE(k + 2, sb);
        short8 a[4], b[4];
#pragma unroll
        for (int m = 0; m < 4; ++m)
            a[m] = *reinterpret_cast<const short8*>(&As[cb][(wr * 64 + m * 16 + lm) * BK + lg * 8]);
#pragma unroll
        for (int n = 0; n < 4; ++n)
            b[n] = *reinterpret_cast<const short8*>(&Bs[cb][(wc * 64 + n * 16 + lm) * BK + lg * 8]);
#pragma unroll
        for (int m = 0; m < 4; ++m)
#pragma unroll
            for (int n = 0; n < 4; ++n)
                acc[m][n] = __builtin_amdgcn_mfma_f32_16x16x32_bf16(a[m], b[n], acc[m][n], 0, 0, 0);
        if (k + 1 < NT) {
            if (k + 2 < NT) asm volatile("s_waitcnt vmcnt(4)" ::: "memory");
            else            asm volatile("s_waitcnt vmcnt(0)" ::: "memory");
            __builtin_amdgcn_s_barrier();
            asm volatile("" ::: "memory");
        }
        cb = (cb == 2) ? 0 : cb + 1;
        sb = (sb == 2) ? 0 : sb + 1;
    }
#undef QSTAGE

    const int reg = blockIdx.x >> 3;    // 0=q, 1=k, 2=v (uniform per block)
    if (reg < 2) {
        const float qs = (reg == 0) ? (0.125f * 1.4426950408889634f) : 1.0f;
        const int odd = lm & 1;
#pragma unroll
        for (int m = 0; m < 4; ++m) {
#pragma unroll
            for (int r = 0; r < 4; ++r) {
                const int row = brow + wr * 64 + m * 16 + lg * 4 + r;
                const int s   = row & (SEQ - 1);
                const size_t base = (size_t)row * DQKV + bcol + wc * 64 + lm;
#pragma unroll
                for (int n = 0; n < 4; ++n) {
                    float v  = acc[m][n][r];
                    float pv = __shfl_xor(v, 1);
                    const int fi = (n * 16 + lm) >> 1;
                    float2 cs = reinterpret_cast<const float2*>(tab)[s * 32 + fi];
                    float c = cs.x * qs, sn = cs.y * qs;
                    float out = odd ? (pv * sn + v * c) : (v * c - pv * sn);
                    qkv[base + n * 16] = f2b(out);
                }
            }
        }
    } else {
        const int b = brow >> 11;
#pragma unroll
        for (int m = 0; m < 4; ++m) {
            const int s0 = (brow + wr * 64 + m * 16 + lg * 4) & (SEQ - 1);
#pragma unroll
            for (int n = 0; n < 4; ++n) {
                const int vcol = bcol + wc * 64 + n * 16 + lm - 2 * DM;
                const int h = vcol >> 6, d = vcol & 63;
                us4 val = { f2b(acc[m][n][0]), f2b(acc[m][n][1]),
                            f2b(acc[m][n][2]), f2b(acc[m][n][3]) };
                *reinterpret_cast<us4*>(vT + (size_t)((b * NH + h) * DH + d) * SEQ + s0) = val;
            }
        }
    }
}

// ---------------------------------------------------------------------------
// MFMA flash attention v15: v12 split-K pairs + CROSS-BLOCK key split.
// Grid 2048: (bh, 64q chunk) handled by TWO blocks:
//   split0 = key-tiles [0, ceil(nb/2)), split1 = [ceil(nb/2), nb).
// Max block length 33 -> 17 iters, and 8 queued blocks/CU against the
// 4-block LDS residency cap -> backfill (occupancy no longer decays).
// Each block pair-merges internally (as v12), then writes UNNORMALIZED
// partials: O bf16 (P0/P1, attn layout) + per-row (m,l) into ML.
// attn_merge combines the two splits (same math as the pair merge).
// Mask condition: blk == chunk (exact for both splits; empty split1 for
// chunk 0 yields m=-3e38, l=0 -> f=0 in merge).
// ---------------------------------------------------------------------------
__global__ __launch_bounds__(256, 4) void attn_mfma(const unsigned short* __restrict__ qkv,
                                                    const unsigned short* __restrict__ vT,
                                                    unsigned short* __restrict__ P0,
                                                    unsigned short* __restrict__ P1,
                                                    float* __restrict__ ML) {
    const int tid  = threadIdx.x;
    const int wid  = tid >> 6;
    const int lane = tid & 63;
    const int l31 = lane & 31, lo = lane >> 5;
    const int tile = wid >> 1;       // 0,1: q sub-tile
    const int half = wid & 1;        // 0,1: key half within a tile

    const int bid  = blockIdx.x;     // [0,2048)
    const int xcd  = bid & 7;
    const int r2   = bid >> 3;       // [0,256)
    const int split = r2 & 1;
    const int u    = r2 >> 1;        // [0,128)
    const int j    = u & 31;
    const int bh_hi = u >> 5;        // 0..3
    const int chunk = (bh_hi & 1) ? (31 - j) : j;
    const int bh = xcd + 8 * bh_hi;
    const int b = bh >> 4, h = bh & 15;
    const int qbase = chunk * 64 + tile * 32;

    const int nb_total = chunk + 1;
    const int nhalf = (nb_total + 1) >> 1;
    const int t0 = split ? nhalf : 0;
    const int t1 = split ? nb_total : nhalf;

    __shared__ unsigned short Kl[2][4096];     // [32 rows][256B], swizzled (16KB)
    __shared__ unsigned short Vl[2][4096];     // (16KB)

    const unsigned short* kb = qkv + ((size_t)b * SEQ) * DQKV + DM + h * DH;
    const unsigned short* vb = vT + ((size_t)bh) * DH * SEQ;

    const int pr  = tid >> 4;               // 0..15
    const int st  = tid & 15;
    const int c16 = st ^ pr;
    const int hf  = c16 >> 3;
    const int cc  = c16 & 7;
    const unsigned short* kst0 = kb + (size_t)(pr + hf * 32) * DQKV + cc * 8;
    const unsigned short* kst1 = kst0 + (size_t)16 * DQKV;
    const unsigned short* vst0 = vb + (size_t)(pr + hf * 32) * SEQ + cc * 8;
    const unsigned short* vst1 = vst0 + 16 * SEQ;
    const int sdst = wid * 512;

    const unsigned short* qr = qkv + ((size_t)(b * SEQ + qbase + l31)) * DQKV + h * DH + lo * 8;
    short8 qb4[4];
#pragma unroll
    for (int dc = 0; dc < 4; ++dc)
        qb4[dc] = *reinterpret_cast<const short8*>(qr + dc * 16);

    f32x16 oA = {0,0,0,0,0,0,0,0,0,0,0,0,0,0,0,0};
    f32x16 oB = {0,0,0,0,0,0,0,0,0,0,0,0,0,0,0,0};
    float mrun = -3.0e38f, lrun = 0.f;

    // prologue: stage tile t0 (keys [t0*64, t0*64+64), always in-range)
    {
        const size_t pk0 = (size_t)(t0 << 6) * DQKV;
        const int    pv0 = t0 << 6;
        gload_lds16(kst0 + pk0, &Kl[0][sdst]);
        gload_lds16(kst1 + pk0, &Kl[0][2048 + sdst]);
        gload_lds16(vst0 + pv0, &Vl[0][sdst]);
        gload_lds16(vst1 + pv0, &Vl[0][2048 + sdst]);
    }
    __syncthreads();

    const int lx = l31 & 15;
    int buf = 0;
    for (int blk = t0; blk < t1; ++blk) {
        const int kbase = blk << 6;

        if (blk + 1 < t1) {
            const size_t ko = (size_t)(kbase + 64) * DQKV;
            const int    vo = kbase + 64;
            gload_lds16(kst0 + ko, &Kl[buf ^ 1][sdst]);
            gload_lds16(kst1 + ko, &Kl[buf ^ 1][2048 + sdst]);
            gload_lds16(vst0 + vo, &Vl[buf ^ 1][sdst]);
            gload_lds16(vst1 + vo, &Vl[buf ^ 1][2048 + sdst]);
        }

        const char* Kb = (const char*)&Kl[buf][0];
        const char* Vb = (const char*)&Vl[buf][0];

        f32x16 S = {0,0,0,0,0,0,0,0,0,0,0,0,0,0,0,0};
        __builtin_amdgcn_s_setprio(1);
#pragma unroll
        for (int dc = 0; dc < 4; ++dc) {
            const int ss = ((half * 8 + dc * 2 + lo) ^ lx) << 4;
            short8 k0 = *reinterpret_cast<const short8*>(Kb + l31 * 256 + ss);
            S = __builtin_amdgcn_mfma_f32_32x32x16_bf16(k0, qb4[dc], S, 0, 0, 0);
        }
        __builtin_amdgcn_s_setprio(0);

        short8 vf[2][2];
#pragma unroll
        for (int kc = 0; kc < 2; ++kc) {
#pragma unroll
            for (int dh = 0; dh < 2; ++dh) {
                const int sts = ((dh * 8 + (half * 2 + kc) * 2 + lo) ^ lx) << 4;
                vf[kc][dh] = *reinterpret_cast<const short8*>(Vb + l31 * 256 + sts);
            }
        }

        float s[16];
#pragma unroll
        for (int r = 0; r < 16; ++r) s[r] = S[r];

        // causal mask: only the diagonal tile (blk == chunk) crosses
        if (blk == chunk) {
            const int q = qbase + l31;
#pragma unroll
            for (int r = 0; r < 16; ++r) {
                const int kk = kbase + half * 32 + (r & 3) + 8 * (r >> 2) + 4 * lo;
                s[r] = (kk <= q) ? s[r] : -INFINITY;
            }
        }

        float t0m = fmaxf(s[0], s[1]),  t1m = fmaxf(s[2], s[3]);
        float t2m = fmaxf(s[4], s[5]),  t3m = fmaxf(s[6], s[7]);
        float t4m = fmaxf(s[8], s[9]),  t5m = fmaxf(s[10], s[11]);
        float t6m = fmaxf(s[12], s[13]), t7m = fmaxf(s[14], s[15]);
        float lmax = fmaxf(fmaxf(fmaxf(t0m, t1m), fmaxf(t2m, t3m)),
                           fmaxf(fmaxf(t4m, t5m), fmaxf(t6m, t7m)));

        if (!__all(lmax - mrun <= 8.0f)) {
            float mx = fmaxf(lmax, __shfl_xor(lmax, 32));
            float mn = fmaxf(mrun, mx);
            float fsc = fexp2(mrun - mn);
            mrun = mn;
            lrun *= fsc;
#pragma unroll
            for (int r = 0; r < 16; ++r) {
                float fr = __shfl(fsc, (r & 3) + 8 * (r >> 2) + 4 * lo);
                oA[r] *= fr; oB[r] *= fr;
            }
        }

#pragma unroll
        for (int r = 0; r < 16; ++r) s[r] = fexp2(s[r] - mrun);

        float a0 = (s[0] + s[1]) + (s[2] + s[3]);
        float a1 = (s[4] + s[5]) + (s[6] + s[7]);
        float a2 = (s[8] + s[9]) + (s[10] + s[11]);
        float a3 = (s[12] + s[13]) + (s[14] + s[15]);
        float ps = (a0 + a1) + (a2 + a3);
        ps += __shfl_xor(ps, 32);
        lrun += ps;

        unsigned int pf[2][4];
        {
            unsigned int a0u = pk2b(s[0], s[1]);
            unsigned int b0u = pk2b(s[4], s[5]);
            swap32(a0u, b0u);
            unsigned int a1u = pk2b(s[2], s[3]);
            unsigned int b1u = pk2b(s[6], s[7]);
            swap32(a1u, b1u);
            pf[0][0] = a0u; pf[0][1] = a1u; pf[0][2] = b0u; pf[0][3] = b1u;
            unsigned int a2u = pk2b(s[8], s[9]);
            unsigned int b2u = pk2b(s[12], s[13]);
            swap32(a2u, b2u);
            unsigned int a3u = pk2b(s[10], s[11]);
            unsigned int b3u = pk2b(s[14], s[15]);
            swap32(a3u, b3u);
            pf[1][0] = a2u; pf[1][1] = a3u; pf[1][2] = b2u; pf[1][3] = b3u;
        }

        __builtin_amdgcn_s_setprio(1);
#pragma unroll
        for (int kc = 0; kc < 2; ++kc) {
            union { unsigned int u[4]; short8 v; } P;
            P.u[0] = pf[kc][0]; P.u[1] = pf[kc][1]; P.u[2] = pf[kc][2]; P.u[3] = pf[kc][3];
            oA = __builtin_amdgcn_mfma_f32_32x32x16_bf16(P.v, vf[kc][0], oA, 0, 0, 0);
            oB = __builtin_amdgcn_mfma_f32_32x32x16_bf16(P.v, vf[kc][1], oB, 0, 0, 0);
        }
        __builtin_amdgcn_s_setprio(0);

        __syncthreads();
        buf ^= 1;
    }

    // -------- pair merge (within block) then UNNORMALIZED partial write ---
    float* mbase = (tile == 0) ? (float*)&Kl[0][0] : (float*)&Vl[0][0];
    if (half == 0) {
#pragma unroll
        for (int g = 0; g < 8; ++g) {
            f32x4 w;
#pragma unroll
            for (int t = 0; t < 4; ++t)
                w[t] = (g < 4) ? oA[(g & 3) * 4 + t] : oB[(g & 3) * 4 + t];
            *reinterpret_cast<f32x4*>(mbase + lane * 32 + ((g ^ (lane & 7)) * 4)) = w;
        }
        if (lo == 0) {
            mbase[2048 + l31 * 2]     = mrun;
            mbase[2048 + l31 * 2 + 1] = lrun;
        }
    }
    __syncthreads();
    if (half == 1) {
        unsigned short* pO = split ? P1 : P0;
        float* Mp = ML + (size_t)split * 131072;   // [M | L] per split
        float* Lp = Mp + 65536;

        const float m0 = mbase[2048 + l31 * 2];
        const float l0 = mbase[2048 + l31 * 2 + 1];
        const float ms = fmaxf(m0, mrun);
        const float f0 = fexp2(m0 - ms);
        const float f1 = fexp2(mrun - ms);
        const float lp = l0 * f0 + lrun * f1;
        if (lo == 0) {
            const int mi = (b * SEQ + qbase + l31) * 16 + h;
            Mp[mi] = ms;
            Lp[mi] = lp;
        }
#pragma unroll
        for (int g = 0; g < 8; ++g) {
            f32x4 rd = *reinterpret_cast<const f32x4*>(mbase + lane * 32 + ((g ^ (lane & 7)) * 4));
#pragma unroll
            for (int t = 0; t < 4; ++t) {
                const int r = (g & 3) * 4 + t;
                const float mine = (g < 4) ? oA[r] : oB[r];
                const int qr2 = (r & 3) + 8 * (r >> 2) + 4 * lo;
                const float f0q = __shfl(f0, qr2);
                const float f1q = __shfl(f1, qr2);
                const float val = rd[t] * f0q + mine * f1q;   // unnormalized
                const size_t rowoff = ((size_t)(b * SEQ + qbase + qr2)) * DM + h * DH + ((g < 4) ? 0 : 32);
                pO[rowoff + l31] = f2b(val);
            }
        }
    }
}

// ---------------------------------------------------------------------------
// Merge the two split partials: out = (O0*f0 + O1*f1) / (l0*f0 + l1*f1).
// In-place into P0's region (each element read once, then overwritten).
// ---------------------------------------------------------------------------
__global__ __launch_bounds__(256) void attn_merge(const unsigned short* __restrict__ P0,
                                                  const unsigned short* __restrict__ P1,
                                                  const float* __restrict__ ML,
                                                  unsigned short* __restrict__ out) {
    const int idx = blockIdx.x * 256 + threadIdx.x;   // [0, 524288)
    const int rh = idx >> 3;                          // (row,h) [0,65536)
    const int d0 = (idx & 7) * 8;
    const int row = rh >> 4, h = rh & 15;

    const float m0 = ML[rh];
    const float l0 = ML[65536 + rh];
    const float m1 = ML[131072 + rh];
    const float l1 = ML[196608 + rh];
    const float ms = fmaxf(m0, m1);
    const float f0 = fexp2(m0 - ms);
    const float f1 = fexp2(m1 - ms);
    const float li = 1.0f / (l0 * f0 + l1 * f1);

    const size_t base = (size_t)row * DM + h * DH + d0;
    us4 a0 = *reinterpret_cast<const us4*>(P0 + base);
    us4 a1 = *reinterpret_cast<const us4*>(P0 + base + 4);
    us4 c0 = *reinterpret_cast<const us4*>(P1 + base);
    us4 c1 = *reinterpret_cast<const us4*>(P1 + base + 4);
    us4 o0v, o1v;
#pragma unroll
    for (int t = 0; t < 4; ++t) {
        o0v[t] = f2b((b2f(a0[t]) * f0 + b2f(c0[t]) * f1) * li);
        o1v[t] = f2b((b2f(a1[t]) * f0 + b2f(c1[t]) * f1) * li);
    }
    *reinterpret_cast<us4*>(out + base)     = o0v;
    *reinterpret_cast<us4*>(out + base + 4) = o1v;
}

// ---------------------------------------------------------------------------
extern "C" void kernel_launch(void* const* d_in, const int* in_sizes, int n_in,
                              void* d_out, int out_size, void* d_ws, size_t ws_size,
                              hipStream_t stream) {
    const float* x  = (const float*)d_in[0];
    const float* wq = (const float*)d_in[1];
    const float* wk = (const float*)d_in[2];
    const float* wv = (const float*)d_in[3];
    const float* wo = (const float*)d_in[4];
    float* out = (float*)d_out;

    char* ws = (char*)d_ws;
    const size_t MB = 1024 * 1024;
    unsigned short* xb      = (unsigned short*)(ws);             // 8 MB (later P0 + attn_bf)
    unsigned short* wqkv    = (unsigned short*)(ws + 8 * MB);    // 6 MB
    unsigned short* wob     = (unsigned short*)(ws + 14 * MB);   // 2 MB (needed by gemm_out)
    unsigned short* qkv     = (unsigned short*)(ws + 16 * MB);   // 24 MB
    unsigned short* vT      = (unsigned short*)(ws + 40 * MB);   // 8 MB
    float*          ropetab = (float*)(ws + 48 * MB);            // 512 KB (dead after gemm_qkv)
    unsigned short* P0      = xb;                                // 8 MB (xb dead after gemm_qkv)
    unsigned short* P1      = (unsigned short*)(ws + 48 * MB);   // 8 MB (overlaps dead ropetab)
    float*          ML      = (float*)(ws + 56 * MB);            // 1 MB (4 x 65536 f32)
    unsigned short* attn_bf = P0;                                // merge writes in-place

    const int cvt_grid = (NX4 + 4 * NW4 + SEQ * 32) / 256;
    cvt_all<<<cvt_grid, 256, 0, stream>>>(x, wq, wk, wv, wo, xb, wqkv, wob, ropetab);

    gemm_qkv<<<dim3(DQKV / BN, MROWS / BM), 256, 0, stream>>>(xb, wqkv, qkv, vT, ropetab);

    attn_mfma<<<2048, 256, 0, stream>>>(qkv, vT, P0, P1, ML);

    attn_merge<<<2048, 256, 0, stream>>>(P0, P1, ML, attn_bf);

    gemm_out<<<dim3(DM / 64, MROWS / 128), 256, 0, stream>>>(attn_bf, wob, out);
}

// Round 21
// 112.805 us; speedup vs baseline: 1.0422x; 1.0422x over previous
//
#include <hip/hip_runtime.h>
#include <hip/hip_bf16.h>
#include <math.h>

// Problem constants
#define B_SZ   2
#define SEQ    2048
#define DM     1024
#define NH     16
#define DH     64
#define MROWS  (B_SZ * SEQ)      // 4096
#define DQKV   (3 * DM)          // 3072, interleaved qkv row stride

typedef __attribute__((ext_vector_type(8))) short short8;
typedef __attribute__((ext_vector_type(4))) float f32x4;
typedef __attribute__((ext_vector_type(16))) float f32x16;
typedef __attribute__((ext_vector_type(4))) unsigned short us4;
typedef __attribute__((ext_vector_type(2))) unsigned int u32x2;

__device__ __forceinline__ float b2f(unsigned short u) {
    union { float f; unsigned int i; } x; x.i = ((unsigned int)u) << 16; return x.f;
}
__device__ __forceinline__ unsigned short f2b(float f) {
    union { float f; unsigned int i; } x; x.f = f;
    return (unsigned short)((x.i + 0x7fffu + ((x.i >> 16) & 1u)) >> 16);
}
__device__ __forceinline__ unsigned int pk2b(float a, float b) {
    float2 f2; f2.x = a; f2.y = b;
    __hip_bfloat162 hb = __float22bfloat162_rn(f2);
    return *reinterpret_cast<unsigned int*>(&hb);
}
__device__ __forceinline__ float fexp2(float x) {
    float r; asm("v_exp_f32 %0, %1" : "=v"(r) : "v"(x)); return r;
}
__device__ __forceinline__ void swap32(unsigned int& a, unsigned int& b) {
    asm("v_permlane32_swap_b32 %0, %1" : "+v"(a), "+v"(b));
}

// async global->LDS, 16B per lane; lds base must be wave-uniform (HW adds lane*16)
__device__ __forceinline__ void gload_lds16(const unsigned short* g, unsigned short* lds_base_uniform) {
    __builtin_amdgcn_global_load_lds(
        (const __attribute__((address_space(1))) unsigned int*)g,
        (__attribute__((address_space(3))) unsigned int*)lds_base_uniform,
        16, 0, 0);
}

// ---------------------------------------------------------------------------
// One-shot prep: conversions + RoPE table.
// ---------------------------------------------------------------------------
#define NX4 (MROWS * DM / 4)     // 2^20 vec4
#define NW4 (DM * DM / 4)        // 2^18 vec4

__global__ __launch_bounds__(256) void cvt_all(const float* __restrict__ x,
                                               const float* __restrict__ wq,
                                               const float* __restrict__ wk,
                                               const float* __restrict__ wv,
                                               const float* __restrict__ wo,
                                               unsigned short* __restrict__ xb,
                                               unsigned short* __restrict__ wqkv,
                                               unsigned short* __restrict__ wob,
                                               float* __restrict__ tab) {
    const int i = blockIdx.x * 256 + threadIdx.x;
    const int ncvt = NX4 + 4 * NW4;
    if (i < ncvt) {
        const float* src; unsigned short* dst; int off;
        if (i < NX4) { src = x; dst = xb; off = i; }
        else {
            int j = i - NX4;
            int w = j >> 18;
            off = j & (NW4 - 1);
            src = (w == 0) ? wq : (w == 1) ? wk : (w == 2) ? wv : wo;
            dst = (w < 3) ? wqkv + (size_t)w * DM * DM : wob;
        }
        float4 v = reinterpret_cast<const float4*>(src)[off];
        us4 o = { f2b(v.x), f2b(v.y), f2b(v.z), f2b(v.w) };
        reinterpret_cast<us4*>(dst)[off] = o;
    } else {
        int t = i - ncvt;               // [0, SEQ*32)
        if (t < SEQ * 32) {
            int s = t >> 5, fi = t & 31;
            float inv = powf(10000.0f, -(float)fi / 32.0f);
            float ang = (float)s * inv;
            tab[2 * t]     = cosf(ang);
            tab[2 * t + 1] = sinf(ang);
        }
    }
}

// ---------------------------------------------------------------------------
// Triple-buffered counted-vmcnt bf16 MFMA GEMMs.
// ---------------------------------------------------------------------------
#define BM 128
#define BN 128
#define BK 32

__global__ __launch_bounds__(256, 2) void gemm_out(const unsigned short* __restrict__ A,
                                                   const unsigned short* __restrict__ B,
                                                   float* __restrict__ Cout) {
    __shared__ unsigned short As[3][128 * BK];   // 3 x 8 KB
    __shared__ unsigned short Bs[3][64 * BK];    // 3 x 4 KB
    const int tid  = threadIdx.x;
    const int lane = tid & 63, wid = tid >> 6;
    const int lm = lane & 15, lg = lane >> 4;
    const int brow = blockIdx.y * 128, bcol = blockIdx.x * 64;
    const int K = DM, N = DM;
    const int NT = K / BK;     // 32

    f32x4 acc[2][4] = {};

    const int rA  = tid >> 2;
    const int kc8 = (tid & 3) * 8;
    const unsigned short* gA0 = A + (size_t)(brow + rA) * K + kc8;
    const unsigned short* gA1 = A + (size_t)(brow + 64 + rA) * K + kc8;
    const unsigned short* gB0 = B + (size_t)(bcol + rA) * K + kc8;
    const int la = wid * 512;

#define OSTAGE(t, bi)                                        \
    {                                                        \
        const int _o = (t) * BK;                             \
        gload_lds16(gA0 + _o, &As[bi][la]);                  \
        gload_lds16(gA1 + _o, &As[bi][2048 + la]);           \
        gload_lds16(gB0 + _o, &Bs[bi][la]);                  \
    }

    OSTAGE(0, 0);
    OSTAGE(1, 1);
    asm volatile("s_waitcnt vmcnt(3)" ::: "memory");
    __builtin_amdgcn_s_barrier();
    asm volatile("" ::: "memory");

    int cb = 0, sb = 2;
    for (int k = 0; k < NT; ++k) {
        if (k + 2 < NT) OSTAGE(k + 2, sb);
        short8 a[2], b[4];
#pragma unroll
        for (int m = 0; m < 2; ++m)
            a[m] = *reinterpret_cast<const short8*>(&As[cb][(wid * 32 + m * 16 + lm) * BK + lg * 8]);
#pragma unroll
        for (int n = 0; n < 4; ++n)
            b[n] = *reinterpret_cast<const short8*>(&Bs[cb][(n * 16 + lm) * BK + lg * 8]);
#pragma unroll
        for (int m = 0; m < 2; ++m)
#pragma unroll
            for (int n = 0; n < 4; ++n)
                acc[m][n] = __builtin_amdgcn_mfma_f32_16x16x32_bf16(a[m], b[n], acc[m][n], 0, 0, 0);
        if (k + 1 < NT) {
            if (k + 2 < NT) asm volatile("s_waitcnt vmcnt(3)" ::: "memory");
            else            asm volatile("s_waitcnt vmcnt(0)" ::: "memory");
            __builtin_amdgcn_s_barrier();
            asm volatile("" ::: "memory");
        }
        cb = (cb == 2) ? 0 : cb + 1;
        sb = (sb == 2) ? 0 : sb + 1;
    }
#undef OSTAGE

#pragma unroll
    for (int m = 0; m < 2; ++m) {
#pragma unroll
        for (int r = 0; r < 4; ++r) {
            const size_t base = (size_t)(brow + wid * 32 + m * 16 + lg * 4 + r) * N + bcol + lm;
#pragma unroll
            for (int n = 0; n < 4; ++n)
                Cout[base + n * 16] = acc[m][n][r];
        }
    }
}

__global__ __launch_bounds__(256, 2) void gemm_qkv(const unsigned short* __restrict__ A,
                                                   const unsigned short* __restrict__ B,
                                                   unsigned short* __restrict__ qkv,
                                                   unsigned short* __restrict__ vT,
                                                   const float* __restrict__ tab) {
    __shared__ unsigned short As[3][BM * BK];   // 3 x 8 KB
    __shared__ unsigned short Bs[3][BN * BK];   // 3 x 8 KB
    const int tid  = threadIdx.x;
    const int lane = tid & 63, wid = tid >> 6;
    const int wr = wid >> 1, wc = wid & 1;
    const int lm = lane & 15, lg = lane >> 4;
    const int brow = blockIdx.y * BM, bcol = blockIdx.x * BN;
    const int K = DM;
    const int NT = K / BK;     // 32

    f32x4 acc[4][4] = {};

    const int rA  = tid >> 2;
    const int kc8 = (tid & 3) * 8;
    const unsigned short* gA0 = A + (size_t)(brow + rA) * K + kc8;
    const unsigned short* gA1 = A + (size_t)(brow + 64 + rA) * K + kc8;
    const unsigned short* gB0 = B + (size_t)(bcol + rA) * K + kc8;
    const unsigned short* gB1 = B + (size_t)(bcol + 64 + rA) * K + kc8;
    const int la = wid * 512;

#define QSTAGE(t, bi)                                        \
    {                                                        \
        const int _o = (t) * BK;                             \
        gload_lds16(gA0 + _o, &As[bi][la]);                  \
        gload_lds16(gA1 + _o, &As[bi][2048 + la]);           \
        gload_lds16(gB0 + _o, &Bs[bi][la]);                  \
        gload_lds16(gB1 + _o, &Bs[bi][2048 + la]);           \
    }

    QSTAGE(0, 0);
    QSTAGE(1, 1);
    asm volatile("s_waitcnt vmcnt(4)" ::: "memory");
    __builtin_amdgcn_s_barrier();
    asm volatile("" ::: "memory");

    int cb = 0, sb = 2;
    for (int k = 0; k < NT; ++k) {
        if (k + 2 < NT) QSTAGE(k + 2, sb);
        short8 a[4], b[4];
#pragma unroll
        for (int m = 0; m < 4; ++m)
            a[m] = *reinterpret_cast<const short8*>(&As[cb][(wr * 64 + m * 16 + lm) * BK + lg * 8]);
#pragma unroll
        for (int n = 0; n < 4; ++n)
            b[n] = *reinterpret_cast<const short8*>(&Bs[cb][(wc * 64 + n * 16 + lm) * BK + lg * 8]);
#pragma unroll
        for (int m = 0; m < 4; ++m)
#pragma unroll
            for (int n = 0; n < 4; ++n)
                acc[m][n] = __builtin_amdgcn_mfma_f32_16x16x32_bf16(a[m], b[n], acc[m][n], 0, 0, 0);
        if (k + 1 < NT) {
            if (k + 2 < NT) asm volatile("s_waitcnt vmcnt(4)" ::: "memory");
            else            asm volatile("s_waitcnt vmcnt(0)" ::: "memory");
            __builtin_amdgcn_s_barrier();
            asm volatile("" ::: "memory");
        }
        cb = (cb == 2) ? 0 : cb + 1;
        sb = (sb == 2) ? 0 : sb + 1;
    }
#undef QSTAGE

    const int reg = blockIdx.x >> 3;    // 0=q, 1=k, 2=v (uniform per block)
    if (reg < 2) {
        const float qs = (reg == 0) ? (0.125f * 1.4426950408889634f) : 1.0f;
        const int odd = lm & 1;
#pragma unroll
        for (int m = 0; m < 4; ++m) {
#pragma unroll
            for (int r = 0; r < 4; ++r) {
                const int row = brow + wr * 64 + m * 16 + lg * 4 + r;
                const int s   = row & (SEQ - 1);
                const size_t base = (size_t)row * DQKV + bcol + wc * 64 + lm;
#pragma unroll
                for (int n = 0; n < 4; ++n) {
                    float v  = acc[m][n][r];
                    float pv = __shfl_xor(v, 1);
                    const int fi = (n * 16 + lm) >> 1;
                    float2 cs = reinterpret_cast<const float2*>(tab)[s * 32 + fi];
                    float c = cs.x * qs, sn = cs.y * qs;
                    float out = odd ? (pv * sn + v * c) : (v * c - pv * sn);
                    qkv[base + n * 16] = f2b(out);
                }
            }
        }
    } else {
        const int b = brow >> 11;
#pragma unroll
        for (int m = 0; m < 4; ++m) {
            const int s0 = (brow + wr * 64 + m * 16 + lg * 4) & (SEQ - 1);
#pragma unroll
            for (int n = 0; n < 4; ++n) {
                const int vcol = bcol + wc * 64 + n * 16 + lm - 2 * DM;
                const int h = vcol >> 6, d = vcol & 63;
                us4 val = { f2b(acc[m][n][0]), f2b(acc[m][n][1]),
                            f2b(acc[m][n][2]), f2b(acc[m][n][3]) };
                *reinterpret_cast<us4*>(vT + (size_t)((b * NH + h) * DH + d) * SEQ + s0) = val;
            }
        }
    }
}

// ---------------------------------------------------------------------------
// MFMA flash attention v12 (best verified, 45.2 us): split-K wave pairs.
// Block = 64q chunk, 4 waves: (tile = wid>>1) x (half = wid&1).
// 1024 blocks -> 4 blocks/CU, 16 waves/CU. LDS 33KB.
// K/V LDS [32 phys rows][256B], 4-bit XOR slot swizzle (conflict-free).
// Swapped QK^T, in-reg softmax, cvt_pk+permlane P, defer-max, setprio.
// Pair merge via dead K/V LDS; mrun init -3e38 (fully-masked half -> 0).
// ---------------------------------------------------------------------------
__global__ __launch_bounds__(256, 4) void attn_mfma(const unsigned short* __restrict__ qkv,
                                                    const unsigned short* __restrict__ vT,
                                                    unsigned short* __restrict__ o) {
    const int tid  = threadIdx.x;
    const int wid  = tid >> 6;
    const int lane = tid & 63;
    const int l31 = lane & 31, lo = lane >> 5;
    const int tile = wid >> 1;       // 0,1: q sub-tile
    const int half = wid & 1;        // 0,1: key half

    const int bid = blockIdx.x;      // [0,1024)
    const int u   = bid >> 3;        // [0,128)
    const int j   = u & 31;
    const int bh_hi = u >> 5;        // 0..3
    const int chunk = (bh_hi & 1) ? (31 - j) : j;
    const int bh = (bid & 7) + 8 * bh_hi;
    const int b = bh >> 4, h = bh & 15;
    const int qbase = chunk * 64 + tile * 32;
    const int nb = chunk + 1;

    __shared__ unsigned short Kl[2][4096];     // [32 rows][256B], swizzled (16KB)
    __shared__ unsigned short Vl[2][4096];     // (16KB)

    const unsigned short* kb = qkv + ((size_t)b * SEQ) * DQKV + DM + h * DH;
    const unsigned short* vb = vT + ((size_t)bh) * DH * SEQ;

    const int pr  = tid >> 4;               // 0..15
    const int st  = tid & 15;
    const int c16 = st ^ pr;
    const int hf  = c16 >> 3;
    const int cc  = c16 & 7;
    const unsigned short* kst0 = kb + (size_t)(pr + hf * 32) * DQKV + cc * 8;
    const unsigned short* kst1 = kst0 + (size_t)16 * DQKV;
    const unsigned short* vst0 = vb + (size_t)(pr + hf * 32) * SEQ + cc * 8;
    const unsigned short* vst1 = vst0 + 16 * SEQ;
    const int sdst = wid * 512;

    const unsigned short* qr = qkv + ((size_t)(b * SEQ + qbase + l31)) * DQKV + h * DH + lo * 8;
    short8 qb4[4];
#pragma unroll
    for (int dc = 0; dc < 4; ++dc)
        qb4[dc] = *reinterpret_cast<const short8*>(qr + dc * 16);

    f32x16 oA = {0,0,0,0,0,0,0,0,0,0,0,0,0,0,0,0};
    f32x16 oB = {0,0,0,0,0,0,0,0,0,0,0,0,0,0,0,0};
    float mrun = -3.0e38f, lrun = 0.f;

    gload_lds16(kst0, &Kl[0][sdst]);
    gload_lds16(kst1, &Kl[0][2048 + sdst]);
    gload_lds16(vst0, &Vl[0][sdst]);
    gload_lds16(vst1, &Vl[0][2048 + sdst]);
    __syncthreads();

    const int lx = l31 & 15;
    int buf = 0;
    for (int blk = 0; blk < nb; ++blk) {
        const int kbase = blk << 6;

        if (blk + 1 < nb) {
            const size_t ko = (size_t)(kbase + 64) * DQKV;
            const int    vo = kbase + 64;
            gload_lds16(kst0 + ko, &Kl[buf ^ 1][sdst]);
            gload_lds16(kst1 + ko, &Kl[buf ^ 1][2048 + sdst]);
            gload_lds16(vst0 + vo, &Vl[buf ^ 1][sdst]);
            gload_lds16(vst1 + vo, &Vl[buf ^ 1][2048 + sdst]);
        }

        const char* Kb = (const char*)&Kl[buf][0];
        const char* Vb = (const char*)&Vl[buf][0];

        f32x16 S = {0,0,0,0,0,0,0,0,0,0,0,0,0,0,0,0};
        __builtin_amdgcn_s_setprio(1);
#pragma unroll
        for (int dc = 0; dc < 4; ++dc) {
            const int ss = ((half * 8 + dc * 2 + lo) ^ lx) << 4;
            short8 k0 = *reinterpret_cast<const short8*>(Kb + l31 * 256 + ss);
            S = __builtin_amdgcn_mfma_f32_32x32x16_bf16(k0, qb4[dc], S, 0, 0, 0);
        }
        __builtin_amdgcn_s_setprio(0);

        short8 vf[2][2];
#pragma unroll
        for (int kc = 0; kc < 2; ++kc) {
#pragma unroll
            for (int dh = 0; dh < 2; ++dh) {
                const int sts = ((dh * 8 + (half * 2 + kc) * 2 + lo) ^ lx) << 4;
                vf[kc][dh] = *reinterpret_cast<const short8*>(Vb + l31 * 256 + sts);
            }
        }

        float s[16];
#pragma unroll
        for (int r = 0; r < 16; ++r) s[r] = S[r];

        if (blk == nb - 1) {
            const int q = qbase + l31;
#pragma unroll
            for (int r = 0; r < 16; ++r) {
                const int kk = kbase + half * 32 + (r & 3) + 8 * (r >> 2) + 4 * lo;
                s[r] = (kk <= q) ? s[r] : -INFINITY;
            }
        }

        float t0 = fmaxf(s[0], s[1]),  t1 = fmaxf(s[2], s[3]);
        float t2 = fmaxf(s[4], s[5]),  t3 = fmaxf(s[6], s[7]);
        float t4 = fmaxf(s[8], s[9]),  t5 = fmaxf(s[10], s[11]);
        float t6 = fmaxf(s[12], s[13]), t7 = fmaxf(s[14], s[15]);
        float lmax = fmaxf(fmaxf(fmaxf(t0, t1), fmaxf(t2, t3)),
                           fmaxf(fmaxf(t4, t5), fmaxf(t6, t7)));

        if (!__all(lmax - mrun <= 8.0f)) {
            float mx = fmaxf(lmax, __shfl_xor(lmax, 32));
            float mn = fmaxf(mrun, mx);
            float fsc = fexp2(mrun - mn);
            mrun = mn;
            lrun *= fsc;
#pragma unroll
            for (int r = 0; r < 16; ++r) {
                float fr = __shfl(fsc, (r & 3) + 8 * (r >> 2) + 4 * lo);
                oA[r] *= fr; oB[r] *= fr;
            }
        }

#pragma unroll
        for (int r = 0; r < 16; ++r) s[r] = fexp2(s[r] - mrun);

        float a0 = (s[0] + s[1]) + (s[2] + s[3]);
        float a1 = (s[4] + s[5]) + (s[6] + s[7]);
        float a2 = (s[8] + s[9]) + (s[10] + s[11]);
        float a3 = (s[12] + s[13]) + (s[14] + s[15]);
        float ps = (a0 + a1) + (a2 + a3);
        ps += __shfl_xor(ps, 32);
        lrun += ps;

        unsigned int pf[2][4];
        {
            unsigned int a0u = pk2b(s[0], s[1]);
            unsigned int b0u = pk2b(s[4], s[5]);
            swap32(a0u, b0u);
            unsigned int a1u = pk2b(s[2], s[3]);
            unsigned int b1u = pk2b(s[6], s[7]);
            swap32(a1u, b1u);
            pf[0][0] = a0u; pf[0][1] = a1u; pf[0][2] = b0u; pf[0][3] = b1u;
            unsigned int a2u = pk2b(s[8], s[9]);
            unsigned int b2u = pk2b(s[12], s[13]);
            swap32(a2u, b2u);
            unsigned int a3u = pk2b(s[10], s[11]);
            unsigned int b3u = pk2b(s[14], s[15]);
            swap32(a3u, b3u);
            pf[1][0] = a2u; pf[1][1] = a3u; pf[1][2] = b2u; pf[1][3] = b3u;
        }

        __builtin_amdgcn_s_setprio(1);
#pragma unroll
        for (int kc = 0; kc < 2; ++kc) {
            union { unsigned int u[4]; short8 v; } P;
            P.u[0] = pf[kc][0]; P.u[1] = pf[kc][1]; P.u[2] = pf[kc][2]; P.u[3] = pf[kc][3];
            oA = __builtin_amdgcn_mfma_f32_32x32x16_bf16(P.v, vf[kc][0], oA, 0, 0, 0);
            oB = __builtin_amdgcn_mfma_f32_32x32x16_bf16(P.v, vf[kc][1], oB, 0, 0, 0);
        }
        __builtin_amdgcn_s_setprio(0);

        __syncthreads();
        buf ^= 1;
    }

    // -------- pair merge: half0 publishes (m,l,O) via dead K/V LDS --------
    float* mbase = (tile == 0) ? (float*)&Kl[0][0] : (float*)&Vl[0][0];
    if (half == 0) {
#pragma unroll
        for (int g = 0; g < 8; ++g) {
            f32x4 w;
#pragma unroll
            for (int t = 0; t < 4; ++t)
                w[t] = (g < 4) ? oA[(g & 3) * 4 + t] : oB[(g & 3) * 4 + t];
            *reinterpret_cast<f32x4*>(mbase + lane * 32 + ((g ^ (lane & 7)) * 4)) = w;
        }
        if (lo == 0) {
            mbase[2048 + l31 * 2]     = mrun;
            mbase[2048 + l31 * 2 + 1] = lrun;
        }
    }
    __syncthreads();
    if (half == 1) {
        const float m0 = mbase[2048 + l31 * 2];
        const float l0 = mbase[2048 + l31 * 2 + 1];
        const float ms = fmaxf(m0, mrun);
        const float f0 = fexp2(m0 - ms);
        const float f1 = fexp2(mrun - ms);
        const float li = 1.0f / (l0 * f0 + lrun * f1);
#pragma unroll
        for (int g = 0; g < 8; ++g) {
            f32x4 rd = *reinterpret_cast<const f32x4*>(mbase + lane * 32 + ((g ^ (lane & 7)) * 4));
#pragma unroll
            for (int t = 0; t < 4; ++t) {
                const int r = (g & 3) * 4 + t;
                const float mine = (g < 4) ? oA[r] : oB[r];
                const int qr2 = (r & 3) + 8 * (r >> 2) + 4 * lo;
                const float f0q = __shfl(f0, qr2);
                const float f1q = __shfl(f1, qr2);
                const float liq = __shfl(li, qr2);
                const float val = (rd[t] * f0q + mine * f1q) * liq;
                const size_t rowoff = ((size_t)(b * SEQ + qbase + qr2)) * DM + h * DH + ((g < 4) ? 0 : 32);
                o[rowoff + l31] = f2b(val);
            }
        }
    }
}

// ---------------------------------------------------------------------------
extern "C" void kernel_launch(void* const* d_in, const int* in_sizes, int n_in,
                              void* d_out, int out_size, void* d_ws, size_t ws_size,
                              hipStream_t stream) {
    const float* x  = (const float*)d_in[0];
    const float* wq = (const float*)d_in[1];
    const float* wk = (const float*)d_in[2];
    const float* wv = (const float*)d_in[3];
    const float* wo = (const float*)d_in[4];
    float* out = (float*)d_out;

    char* ws = (char*)d_ws;
    const size_t MB = 1024 * 1024;
    unsigned short* xb      = (unsigned short*)(ws);             // 8 MB (reused for attn_bf)
    unsigned short* wqkv    = (unsigned short*)(ws + 8 * MB);    // 6 MB
    unsigned short* wob     = (unsigned short*)(ws + 14 * MB);   // 2 MB
    unsigned short* qkv     = (unsigned short*)(ws + 16 * MB);   // 24 MB
    unsigned short* vT      = (unsigned short*)(ws + 40 * MB);   // 8 MB
    float*          ropetab = (float*)(ws + 48 * MB);            // 512 KB
    unsigned short* attn_bf = xb;

    const int cvt_grid = (NX4 + 4 * NW4 + SEQ * 32) / 256;
    cvt_all<<<cvt_grid, 256, 0, stream>>>(x, wq, wk, wv, wo, xb, wqkv, wob, ropetab);

    gemm_qkv<<<dim3(DQKV / BN, MROWS / BM), 256, 0, stream>>>(xb, wqkv, qkv, vT, ropetab);

    attn_mfma<<<1024, 256, 0, stream>>>(qkv, vT, attn_bf);

    gemm_out<<<dim3(DM / 64, MROWS / 128), 256, 0, stream>>>(attn_bf, wob, out);
}